// Round 1
// baseline (2153.752 us; speedup 1.0000x reference)
//
#include <hip/hip_runtime.h>

#define B_SZ 32
#define N_TOK 4096
#define FEAT 768
#define DIM 256
#define NSLOT 16
#define NH 4
#define DH 64
#define M_TOKENS 131072   // B_SZ * N_TOK
#define SCALE 0.125f
#define EPS_ATTN 1e-8f

typedef __attribute__((ext_vector_type(8))) short short8;
typedef __attribute__((ext_vector_type(4))) float floatx4;

__device__ __forceinline__ unsigned short f2bf(float f) {
    unsigned int u = __float_as_uint(f);
    u += 0x7FFFu + ((u >> 16) & 1u);
    return (unsigned short)(u >> 16);
}
__device__ __forceinline__ float bf2f(unsigned short u) {
    return __uint_as_float(((unsigned int)u) << 16);
}

// ---------------- K1: LN row stats (mean, rstd) ----------------
__global__ __launch_bounds__(256) void k_ln_stats(const float* __restrict__ x,
                                                  float2* __restrict__ stats) {
    int w = threadIdx.x >> 6, lane = threadIdx.x & 63;
    int row = blockIdx.x * 4 + w;
    const float4* x4 = (const float4*)(x + (size_t)row * FEAT);
    float s = 0.f, sq = 0.f;
#pragma unroll
    for (int p = 0; p < 3; ++p) {
        float4 v = x4[p * 64 + lane];
        s += v.x + v.y + v.z + v.w;
        sq += v.x * v.x + v.y * v.y + v.z * v.z + v.w * v.w;
    }
#pragma unroll
    for (int off = 32; off >= 1; off >>= 1) {
        s += __shfl_xor(s, off);
        sq += __shfl_xor(sq, off);
    }
    if (lane == 0) {
        float m = s * (1.f / 768.f);
        float var = sq * (1.f / 768.f) - m * m;
        stats[row] = make_float2(m, rsqrtf(var + 1e-5f));
    }
}

// ---------------- K2: fused LN + K/V projection (bf16 MFMA) ----------------
// C[token][n] for n in [0,512): n<256 -> k, n>=256 -> v.  Tile 128x128, BK=32.
__global__ __launch_bounds__(256) void k_kv_gemm(
    const float* __restrict__ x, const float2* __restrict__ stats,
    const float* __restrict__ lg, const float* __restrict__ lb,
    const float* __restrict__ wk, const float* __restrict__ wv,
    unsigned short* __restrict__ kbuf, unsigned short* __restrict__ vbuf) {
    __shared__ unsigned short As[128 * 40];  // padded stride 40 (bank-friendly)
    __shared__ unsigned short Bs[128 * 40];
    int t = threadIdx.x;
    int w = t >> 6, lane = t & 63;
    int n0 = blockIdx.x * 128;
    size_t m0 = (size_t)blockIdx.y * 128;
    const float* wsrc = (n0 < 256) ? wk : wv;
    int nb = (n0 < 256) ? n0 : n0 - 256;
    unsigned short* outb = (n0 < 256) ? kbuf : vbuf;

    int srow = t >> 3, scol = t & 7;  // 32 rows x 8 float4-cols per pass
    float2 st[4];
#pragma unroll
    for (int it = 0; it < 4; ++it) st[it] = stats[m0 + srow + it * 32];

    floatx4 acc[2][8];
#pragma unroll
    for (int mt = 0; mt < 2; ++mt)
#pragma unroll
        for (int nt = 0; nt < 8; ++nt) acc[mt][nt] = (floatx4)(0.f);

    for (int k0 = 0; k0 < FEAT; k0 += 32) {
        float4 gg = *(const float4*)(lg + k0 + scol * 4);
        float4 bb = *(const float4*)(lb + k0 + scol * 4);
#pragma unroll
        for (int it = 0; it < 4; ++it) {
            int row = srow + it * 32;
            // A: fused LayerNorm -> bf16
            float4 a = *(const float4*)(x + (m0 + row) * FEAT + k0 + scol * 4);
            float rstd = st[it].y, mn = st[it].x;
            ushort4 pa;
            pa.x = f2bf((a.x - mn) * rstd * gg.x + bb.x);
            pa.y = f2bf((a.y - mn) * rstd * gg.y + bb.y);
            pa.z = f2bf((a.z - mn) * rstd * gg.z + bb.z);
            pa.w = f2bf((a.w - mn) * rstd * gg.w + bb.w);
            *(ushort4*)(&As[row * 40 + scol * 4]) = pa;
            // B: weights -> bf16 (row n of W, k-contiguous = B^T layout)
            float4 wb = *(const float4*)(wsrc + (size_t)(nb + row) * FEAT + k0 + scol * 4);
            ushort4 pb;
            pb.x = f2bf(wb.x); pb.y = f2bf(wb.y); pb.z = f2bf(wb.z); pb.w = f2bf(wb.w);
            *(ushort4*)(&Bs[row * 40 + scol * 4]) = pb;
        }
        __syncthreads();
        short8 af[2];
#pragma unroll
        for (int mt = 0; mt < 2; ++mt)
            af[mt] = *(const short8*)&As[(w * 32 + mt * 16 + (lane & 15)) * 40 + (lane >> 4) * 8];
        short8 bfr[8];
#pragma unroll
        for (int nt = 0; nt < 8; ++nt)
            bfr[nt] = *(const short8*)&Bs[(nt * 16 + (lane & 15)) * 40 + (lane >> 4) * 8];
#pragma unroll
        for (int mt = 0; mt < 2; ++mt)
#pragma unroll
            for (int nt = 0; nt < 8; ++nt)
                acc[mt][nt] = __builtin_amdgcn_mfma_f32_16x16x32_bf16(af[mt], bfr[nt], acc[mt][nt], 0, 0, 0);
        __syncthreads();
    }
    int cb = nb;
#pragma unroll
    for (int mt = 0; mt < 2; ++mt)
#pragma unroll
        for (int nt = 0; nt < 8; ++nt)
#pragma unroll
            for (int rr = 0; rr < 4; ++rr) {
                size_t row = m0 + w * 32 + mt * 16 + (lane >> 4) * 4 + rr;
                int col = cb + nt * 16 + (lane & 15);
                outb[row * 256 + col] = f2bf(acc[mt][nt][rr]);
            }
}

// ---------------- K3: slots LN + Q projection (+ zero sums/part) ----------------
__global__ __launch_bounds__(256) void k_qproj(
    const float* __restrict__ slots_in, const float* __restrict__ lg,
    const float* __restrict__ lb, const float* __restrict__ wq,
    float* __restrict__ qbuf, float* __restrict__ sums, float* __restrict__ part) {
    __shared__ float s[256], sln[256], red[16];
    int t = threadIdx.x, bx = blockIdx.x, w = t >> 6;
    if (bx < 8) sums[bx * 256 + t] = 0.f;
#pragma unroll
    for (int i = 0; i < 4; ++i) part[(size_t)bx * 1024 + i * 256 + t] = 0.f;
    float v = slots_in[bx * 256 + t];
    s[t] = v;
    float s1 = v, s2 = v * v;
#pragma unroll
    for (int off = 32; off >= 1; off >>= 1) {
        s1 += __shfl_xor(s1, off);
        s2 += __shfl_xor(s2, off);
    }
    if ((t & 63) == 0) { red[w] = s1; red[8 + w] = s2; }
    __syncthreads();
    if (t == 0) {
        float a = red[0] + red[1] + red[2] + red[3];
        float b = red[8] + red[9] + red[10] + red[11];
        float m = a * (1.f / 256.f);
        float var = b * (1.f / 256.f) - m * m;
        red[4] = m;
        red[5] = rsqrtf(var + 1e-5f);
    }
    __syncthreads();
    float m = red[4], rs = red[5];
    sln[t] = (s[t] - m) * rs * lg[t] + lb[t];
    __syncthreads();
    const float4* sl4 = (const float4*)sln;
    const float4* wq4 = (const float4*)(wq + (size_t)t * 256);
    float acc = 0.f;
#pragma unroll 8
    for (int f4 = 0; f4 < 64; ++f4) {
        float4 a = sl4[f4], b = wq4[f4];
        acc += a.x * b.x + a.y * b.y + a.z * b.z + a.w * b.w;
    }
    qbuf[bx * 256 + t] = acc * SCALE;
}

// ---------------- K4: dots + joint softmax over 64 (slot,head) ----------------
// lane l -> (i = l&15, h = l>>4); wave = the softmax axis. q in 64 regs/lane.
__global__ __launch_bounds__(256) void k_dots_softmax(
    const float* __restrict__ qbuf, const unsigned short* __restrict__ kbuf,
    float* __restrict__ attn, float* __restrict__ sums,
    float* __restrict__ attn_out, int last) {
    __shared__ float ks[32 * 272];  // 32 j-rows, per-row h-stride 68 (padded)
    __shared__ float aout[32 * 16];
    int t = threadIdx.x;
    int w = t >> 6, lane = t & 63;
    int b = blockIdx.y;
    int j0 = blockIdx.x * 32;
    float qr[64];
    const float4* q4 = (const float4*)(qbuf + (size_t)b * 4096 + (lane & 15) * 256 + (lane >> 4) * 64);
#pragma unroll
    for (int d4 = 0; d4 < 16; ++d4) {
        float4 qv = q4[d4];
        qr[d4 * 4 + 0] = qv.x; qr[d4 * 4 + 1] = qv.y;
        qr[d4 * 4 + 2] = qv.z; qr[d4 * 4 + 3] = qv.w;
    }
    const uint4* kb4 = (const uint4*)(kbuf + ((size_t)b * 4096 + j0) * 256);
#pragma unroll
    for (int it = 0; it < 4; ++it) {
        int flat = it * 256 + t;
        int jl = flat >> 5, c8 = flat & 31;
        uint4 kv = kb4[jl * 32 + c8];
        int d = c8 * 8, h = d >> 6, dd = d & 63;
        float* dst = ks + jl * 272 + h * 68 + dd;
        *(float4*)dst = make_float4(__uint_as_float(kv.x << 16), __uint_as_float(kv.x & 0xFFFF0000u),
                                    __uint_as_float(kv.y << 16), __uint_as_float(kv.y & 0xFFFF0000u));
        *(float4*)(dst + 4) = make_float4(__uint_as_float(kv.z << 16), __uint_as_float(kv.z & 0xFFFF0000u),
                                          __uint_as_float(kv.w << 16), __uint_as_float(kv.w & 0xFFFF0000u));
    }
    __syncthreads();
    float ssum = 0.f;
    int h = lane >> 4;
    for (int jj = 0; jj < 8; ++jj) {
        int jl = w * 8 + jj;
        const float* krow = ks + jl * 272 + h * 68;
        float acc = 0.f;
#pragma unroll
        for (int d4 = 0; d4 < 16; ++d4) {
            float4 kk = *(const float4*)(krow + d4 * 4);
            acc += qr[d4 * 4] * kk.x + qr[d4 * 4 + 1] * kk.y +
                   qr[d4 * 4 + 2] * kk.z + qr[d4 * 4 + 3] * kk.w;
        }
        float mx = acc;
#pragma unroll
        for (int off = 32; off >= 1; off >>= 1) mx = fmaxf(mx, __shfl_xor(mx, off));
        float e = __expf(acc - mx);
        float sm = e;
#pragma unroll
        for (int off = 32; off >= 1; off >>= 1) sm += __shfl_xor(sm, off);
        float a = e / sm;
        attn[((size_t)b * 4096 + j0 + jl) * 64 + lane] = a;
        ssum += a;
        if (last) {
            float ao = a;
            ao += __shfl_xor(ao, 16);
            ao += __shfl_xor(ao, 32);
            if (lane < 16) aout[jl * 16 + lane] = ao * 0.25f;
        }
    }
    atomicAdd(&sums[b * 64 + lane], ssum);
    if (last) {
        __syncthreads();
#pragma unroll
        for (int it = 0; it < 2; ++it) {
            int flat = it * 256 + t;
            int i = flat >> 5, jl = flat & 31;
            attn_out[((size_t)b * NSLOT + i) * N_TOK + j0 + jl] = aout[jl * 16 + i];
        }
    }
}

// ---------------- K5: updates partials: sum_j v[b,j,h,d] * w[b,i,h,j] ----------------
__global__ __launch_bounds__(256) void k_updates(
    const float* __restrict__ attn, const unsigned short* __restrict__ vbuf,
    const float* __restrict__ sums, float* __restrict__ part) {
    int bx = blockIdx.x;
    int c = bx & 3, h = (bx >> 2) & 3, b = bx >> 4;
    int t = threadIdx.x;
    int i = t >> 4, dg = t & 15;
    float rinv = 1.f / (sums[b * 64 + h * 16 + i] + EPS_ATTN * 4096.f);
    float a0 = 0.f, a1 = 0.f, a2 = 0.f, a3 = 0.f;
    int jbeg = c * 1024;
    for (int j = jbeg; j < jbeg + 1024; ++j) {
        size_t tok = (size_t)b * 4096 + j;
        float wv = (attn[tok * 64 + h * 16 + i] + EPS_ATTN) * rinv;
        ushort4 vv = *(const ushort4*)(vbuf + tok * 256 + h * 64 + dg * 4);
        a0 += wv * bf2f(vv.x);
        a1 += wv * bf2f(vv.y);
        a2 += wv * bf2f(vv.z);
        a3 += wv * bf2f(vv.w);
    }
    *(float4*)(part + ((size_t)c * 512 + b * 16 + i) * 256 + h * 64 + dg * 4) =
        make_float4(a0, a1, a2, a3);
}

// ---------------- K6: GRU + LN + FF (one slot-row per block) ----------------
__global__ __launch_bounds__(256) void k_gru_ff(
    const float* __restrict__ part, const float* __restrict__ slots_prev,
    const float* __restrict__ wih, const float* __restrict__ whh,
    const float* __restrict__ bih, const float* __restrict__ bhh,
    const float* __restrict__ ffg, const float* __restrict__ ffb,
    const float* __restrict__ w1, const float* __restrict__ b1,
    const float* __restrict__ w2, const float* __restrict__ b2,
    float* __restrict__ slots_out, float* __restrict__ dslots, int last) {
    __shared__ float u[256], hp[256], buf[1024], red[16];
    int t = threadIdx.x, r = blockIdx.x, w = t >> 6;
    u[t] = part[(size_t)r * 256 + t] + part[131072 + (size_t)r * 256 + t] +
           part[262144 + (size_t)r * 256 + t] + part[393216 + (size_t)r * 256 + t];
    float hpv = slots_prev[(size_t)r * 256 + t];
    hp[t] = hpv;
    __syncthreads();
    float ai0 = bih[t], ai1 = bih[256 + t], ai2 = bih[512 + t];
    float ah0 = bhh[t], ah1 = bhh[256 + t], ah2 = bhh[512 + t];
    const float4* u4 = (const float4*)u;
    const float4* hp4 = (const float4*)hp;
    const float4* wih4 = (const float4*)wih;
    const float4* whh4 = (const float4*)whh;
#pragma unroll 4
    for (int f4 = 0; f4 < 64; ++f4) {
        float4 uu = u4[f4], hh = hp4[f4];
        float4 wi0 = wih4[(size_t)(0 * 256 + t) * 64 + f4];
        float4 wi1 = wih4[(size_t)(1 * 256 + t) * 64 + f4];
        float4 wi2 = wih4[(size_t)(2 * 256 + t) * 64 + f4];
        ai0 += uu.x * wi0.x + uu.y * wi0.y + uu.z * wi0.z + uu.w * wi0.w;
        ai1 += uu.x * wi1.x + uu.y * wi1.y + uu.z * wi1.z + uu.w * wi1.w;
        ai2 += uu.x * wi2.x + uu.y * wi2.y + uu.z * wi2.z + uu.w * wi2.w;
        float4 wh0 = whh4[(size_t)(0 * 256 + t) * 64 + f4];
        float4 wh1 = whh4[(size_t)(1 * 256 + t) * 64 + f4];
        float4 wh2 = whh4[(size_t)(2 * 256 + t) * 64 + f4];
        ah0 += hh.x * wh0.x + hh.y * wh0.y + hh.z * wh0.z + hh.w * wh0.w;
        ah1 += hh.x * wh1.x + hh.y * wh1.y + hh.z * wh1.z + hh.w * wh1.w;
        ah2 += hh.x * wh2.x + hh.y * wh2.y + hh.z * wh2.z + hh.w * wh2.w;
    }
    float rg = 1.f / (1.f + expf(-(ai0 + ah0)));
    float zg = 1.f / (1.f + expf(-(ai1 + ah1)));
    float ng = tanhf(ai2 + rg * ah2);
    float hn = (1.f - zg) * ng + zg * hpv;
    __syncthreads();  // all reads of u/hp done
    // LayerNorm(hn) over 256
    float s1 = hn, s2 = hn * hn;
#pragma unroll
    for (int off = 32; off >= 1; off >>= 1) {
        s1 += __shfl_xor(s1, off);
        s2 += __shfl_xor(s2, off);
    }
    if ((t & 63) == 0) { red[w] = s1; red[8 + w] = s2; }
    __syncthreads();
    if (t == 0) {
        float a = red[0] + red[1] + red[2] + red[3];
        float bq = red[8] + red[9] + red[10] + red[11];
        float m = a * (1.f / 256.f);
        float var = bq * (1.f / 256.f) - m * m;
        red[4] = m;
        red[5] = rsqrtf(var + 1e-5f);
    }
    __syncthreads();
    float hln = (hn - red[4]) * red[5] * ffg[t] + ffb[t];
    hp[t] = hln;
    __syncthreads();
    const float4* w1_4 = (const float4*)w1;
#pragma unroll
    for (int gg = 0; gg < 4; ++gg) {
        int o = gg * 256 + t;
        float a = b1[o];
#pragma unroll 4
        for (int f4 = 0; f4 < 64; ++f4) {
            float4 hh = hp4[f4];
            float4 ww = w1_4[(size_t)o * 64 + f4];
            a += hh.x * ww.x + hh.y * ww.y + hh.z * ww.z + hh.w * ww.w;
        }
        buf[o] = 0.5f * a * (1.f + erff(a * 0.70710678118654752f));  // exact GELU
    }
    __syncthreads();
    float a2v = b2[t];
    const float4* bf4 = (const float4*)buf;
    const float4* w2_4 = (const float4*)(w2 + (size_t)t * 1024);
#pragma unroll 4
    for (int f4 = 0; f4 < 256; ++f4) {
        float4 hh = bf4[f4];
        float4 ww = w2_4[f4];
        a2v += hh.x * ww.x + hh.y * ww.y + hh.z * ww.z + hh.w * ww.w;
    }
    float outv = hn + a2v;
    slots_out[(size_t)r * 256 + t] = outv;
    if (last) dslots[(size_t)r * 256 + t] = outv;
}

extern "C" void kernel_launch(void* const* d_in, const int* in_sizes, int n_in,
                              void* d_out, int out_size, void* d_ws, size_t ws_size,
                              hipStream_t stream) {
    const float* inputs    = (const float*)d_in[0];
    const float* cond      = (const float*)d_in[1];
    const float* to_q_w    = (const float*)d_in[2];
    const float* to_k_w    = (const float*)d_in[3];
    const float* to_v_w    = (const float*)d_in[4];
    const float* gru_w_ih  = (const float*)d_in[5];
    const float* gru_w_hh  = (const float*)d_in[6];
    const float* gru_b_ih  = (const float*)d_in[7];
    const float* gru_b_hh  = (const float*)d_in[8];
    const float* ln_in_g   = (const float*)d_in[9];
    const float* ln_in_b   = (const float*)d_in[10];
    const float* ln_sl_g   = (const float*)d_in[11];
    const float* ln_sl_b   = (const float*)d_in[12];
    const float* ff_ln_g   = (const float*)d_in[13];
    const float* ff_ln_b   = (const float*)d_in[14];
    const float* ff_w1     = (const float*)d_in[15];
    const float* ff_b1     = (const float*)d_in[16];
    const float* ff_w2     = (const float*)d_in[17];
    const float* ff_b2     = (const float*)d_in[18];

    float* out = (float*)d_out;
    float* out_slots = out;              // 131072
    float* out_attn  = out + 131072;     // 2097152

    // workspace layout (floats)
    float* f = (float*)d_ws;
    float2* stats   = (float2*)f;                 // 131072 float2 = 262144 f
    float* qbuf     = f + 262144;                 // 131072
    float* sums     = qbuf + 131072;              // 2048
    float* part     = sums + 2048;                // 4*512*256 = 524288
    float* slots_ws = part + 524288;              // 131072
    float* attn     = slots_ws + 131072;          // 8388608
    unsigned short* kbuf = (unsigned short*)(attn + 8388608);  // 33554432 bf16
    unsigned short* vbuf = kbuf + 33554432;                    // 33554432 bf16
    // total ~172 MB

    k_ln_stats<<<M_TOKENS / 4, 256, 0, stream>>>(inputs, stats);
    k_kv_gemm<<<dim3(4, M_TOKENS / 128), 256, 0, stream>>>(
        inputs, stats, ln_in_g, ln_in_b, to_k_w, to_v_w, kbuf, vbuf);

    for (int it = 0; it < 3; ++it) {
        const float* sp = (it == 0) ? cond : slots_ws;
        int last = (it == 2) ? 1 : 0;
        k_qproj<<<512, 256, 0, stream>>>(sp, ln_sl_g, ln_sl_b, to_q_w, qbuf, sums, part);
        k_dots_softmax<<<dim3(N_TOK / 32, B_SZ), 256, 0, stream>>>(
            qbuf, kbuf, attn, sums, out_attn, last);
        k_updates<<<512, 256, 0, stream>>>(attn, vbuf, sums, part);
        k_gru_ff<<<512, 256, 0, stream>>>(part, sp, gru_w_ih, gru_w_hh, gru_b_ih, gru_b_hh,
                                          ff_ln_g, ff_ln_b, ff_w1, ff_b1, ff_w2, ff_b2,
                                          slots_ws, out_slots, last);
    }
}

// Round 2
// 1556.715 us; speedup vs baseline: 1.3835x; 1.3835x over previous
//
#include <hip/hip_runtime.h>

#define B_SZ 32
#define N_TOK 4096
#define FEAT 768
#define DIM 256
#define NSLOT 16
#define NH 4
#define DH 64
#define M_TOKENS 131072
#define SCALE 0.125f
#define EPS_ATTN 1e-8f
#define MCHUNK 32768      // kv gemm M-chunk (4 chunks)

typedef unsigned short u16;
typedef __attribute__((ext_vector_type(8))) short short8;
typedef __attribute__((ext_vector_type(4))) float floatx4;

__device__ __forceinline__ u16 f2bf(float f) {
    unsigned int u = __float_as_uint(f);
    u += 0x7FFFu + ((u >> 16) & 1u);
    return (u16)(u >> 16);
}
__device__ __forceinline__ float bf2f(u16 u) {
    return __uint_as_float(((unsigned int)u) << 16);
}
__device__ __forceinline__ void gl_lds16(const void* g, void* l) {
    __builtin_amdgcn_global_load_lds((const __attribute__((address_space(1))) void*)g,
                                     (__attribute__((address_space(3))) void*)l, 16, 0, 0);
}
__device__ __forceinline__ float sigm(float x) { return 1.f / (1.f + expf(-x)); }

// ============ generic bf16 MFMA GEMM: C[M,N] = A[M,K] @ B[N,K]^T ============
// 128x128 tile, BK=32, global_load_lds staging. EPI: 0 kv-split-bf16,
// 1 bf16, 2 f32 (z-batched), 3 gelu+bias->bf16, 4 bias+res->f32 (+out2)
template<int TK, int EPI>
__global__ __launch_bounds__(256) void gemm_bt(
    const u16* __restrict__ A0, const u16* __restrict__ A1,
    const u16* __restrict__ B0, const u16* __restrict__ B1,
    void* __restrict__ C0, void* __restrict__ C1,
    const float* __restrict__ bias, const float* __restrict__ res,
    float* __restrict__ out2, int ldc) {
    __shared__ u16 As[128 * 32];
    __shared__ u16 Bs[128 * 32];
    int t = threadIdx.x, w = t >> 6, lane = t & 63;
    int n0 = blockIdx.x * 128;
    size_t m0 = (size_t)blockIdx.y * 128;
    const u16* A = (blockIdx.z && A1) ? A1 : A0;
    const u16* B = (blockIdx.z && B1) ? B1 : B0;

    floatx4 acc[2][8];
#pragma unroll
    for (int mt = 0; mt < 2; ++mt)
#pragma unroll
        for (int nt = 0; nt < 8; ++nt) acc[mt][nt] = (floatx4)(0.f);

    int srow = (lane >> 2), seg = lane & 3;
    for (int k0 = 0; k0 < TK; k0 += 32) {
#pragma unroll
        for (int c = 0; c < 2; ++c) {
            int row = w * 32 + c * 16 + srow;
            gl_lds16(A + (m0 + row) * TK + k0 + seg * 8, &As[(w * 32 + c * 16) * 32]);
            gl_lds16(B + (size_t)(n0 + row) * TK + k0 + seg * 8, &Bs[(w * 32 + c * 16) * 32]);
        }
        __syncthreads();
        short8 af[2];
#pragma unroll
        for (int mt = 0; mt < 2; ++mt)
            af[mt] = *(const short8*)&As[(w * 32 + mt * 16 + (lane & 15)) * 32 + (lane >> 4) * 8];
        short8 bfr[8];
#pragma unroll
        for (int nt = 0; nt < 8; ++nt)
            bfr[nt] = *(const short8*)&Bs[(nt * 16 + (lane & 15)) * 32 + (lane >> 4) * 8];
#pragma unroll
        for (int mt = 0; mt < 2; ++mt)
#pragma unroll
            for (int nt = 0; nt < 8; ++nt)
                acc[mt][nt] = __builtin_amdgcn_mfma_f32_16x16x32_bf16(af[mt], bfr[nt], acc[mt][nt], 0, 0, 0);
        __syncthreads();
    }
#pragma unroll
    for (int mt = 0; mt < 2; ++mt)
#pragma unroll
        for (int nt = 0; nt < 8; ++nt)
#pragma unroll
            for (int rr = 0; rr < 4; ++rr) {
                size_t row = m0 + w * 32 + mt * 16 + (lane >> 4) * 4 + rr;
                int col = n0 + nt * 16 + (lane & 15);
                float v = acc[mt][nt][rr];
                if (EPI == 0) {
                    if (col < 256) ((u16*)C0)[row * 256 + col] = f2bf(v);
                    else           ((u16*)C1)[row * 256 + col - 256] = f2bf(v);
                } else if (EPI == 1) {
                    ((u16*)C0)[row * (size_t)ldc + col] = f2bf(v);
                } else if (EPI == 2) {
                    float* Cf = (float*)(blockIdx.z ? C1 : C0);
                    Cf[row * (size_t)ldc + col] = v;
                } else if (EPI == 3) {
                    float a = v + bias[col];
                    float g = 0.5f * a * (1.f + erff(a * 0.70710678118654752f));
                    ((u16*)C0)[row * (size_t)ldc + col] = f2bf(g);
                } else if (EPI == 4) {
                    float a = v + bias[col] + res[row * 256 + col];
                    ((float*)C0)[row * 256 + col] = a;
                    out2[row * 256 + col] = a;
                }
            }
}

// ============ LN(inputs) -> bf16, one wave per row ============
__global__ __launch_bounds__(256) void k_ln_bf16(const float* __restrict__ x,
                                                 const float* __restrict__ lg,
                                                 const float* __restrict__ lb,
                                                 u16* __restrict__ xln) {
    int w = threadIdx.x >> 6, lane = threadIdx.x & 63;
    size_t row = (size_t)blockIdx.x * 4 + w;
    const float4* x4 = (const float4*)(x + row * FEAT);
    float4 a[3];
    float s = 0.f, sq = 0.f;
#pragma unroll
    for (int p = 0; p < 3; ++p) {
        a[p] = x4[p * 64 + lane];
        s += a[p].x + a[p].y + a[p].z + a[p].w;
        sq += a[p].x * a[p].x + a[p].y * a[p].y + a[p].z * a[p].z + a[p].w * a[p].w;
    }
#pragma unroll
    for (int off = 32; off >= 1; off >>= 1) {
        s += __shfl_xor(s, off);
        sq += __shfl_xor(sq, off);
    }
    float m = s * (1.f / 768.f);
    float rs = rsqrtf(sq * (1.f / 768.f) - m * m + 1e-5f);
#pragma unroll
    for (int p = 0; p < 3; ++p) {
        float4 g = *(const float4*)(lg + (p * 64 + lane) * 4);
        float4 b = *(const float4*)(lb + (p * 64 + lane) * 4);
        ushort4 o;
        o.x = f2bf((a[p].x - m) * rs * g.x + b.x);
        o.y = f2bf((a[p].y - m) * rs * g.y + b.y);
        o.z = f2bf((a[p].z - m) * rs * g.z + b.z);
        o.w = f2bf((a[p].w - m) * rs * g.w + b.w);
        *(ushort4*)(xln + row * FEAT + (p * 64 + lane) * 4) = o;
    }
}

// ============ weight convert -> bf16 (wkv | wq*SCALE | wih | whh | w1 | w2) ============
#define OFF_WKV 0
#define OFF_WQ  393216
#define OFF_WIH 458752
#define OFF_WHH 655360
#define OFF_W1  851968
#define OFF_W2  1114112
#define W_TOTAL 1376256
__global__ __launch_bounds__(256) void k_wcvt(
    const float* __restrict__ wk, const float* __restrict__ wv,
    const float* __restrict__ wq, const float* __restrict__ wih,
    const float* __restrict__ whh, const float* __restrict__ w1,
    const float* __restrict__ w2, u16* __restrict__ wall) {
    int base = (blockIdx.x * 256 + threadIdx.x) * 4;
    if (base >= W_TOTAL) return;
#pragma unroll
    for (int q = 0; q < 4; ++q) {
        int id = base + q;
        float v;
        if (id < OFF_WQ) {
            int r = id / 768, c = id - r * 768;
            v = (r < 256) ? wk[r * 768 + c] : wv[(r - 256) * 768 + c];
        } else if (id < OFF_WIH) v = wq[id - OFF_WQ] * SCALE;
        else if (id < OFF_WHH)   v = wih[id - OFF_WIH];
        else if (id < OFF_W1)    v = whh[id - OFF_WHH];
        else if (id < OFF_W2)    v = w1[id - OFF_W1];
        else                     v = w2[id - OFF_W2];
        wall[id] = f2bf(v);
    }
}

// ============ vsum[b][h*64+d] = sum_j v ============
__global__ __launch_bounds__(256) void k_vsum(const u16* __restrict__ vb,
                                              float* __restrict__ vsum) {
    __shared__ float vred[4][256];
    int b = blockIdx.x, t = threadIdx.x;
    int c4 = t & 63, jq = t >> 6;
    float ax = 0.f, ay = 0.f, az = 0.f, aw = 0.f;
    for (int j = jq; j < 4096; j += 4) {
        ushort4 vv = *(const ushort4*)(vb + ((size_t)b * 4096 + j) * 256 + c4 * 4);
        ax += bf2f(vv.x); ay += bf2f(vv.y); az += bf2f(vv.z); aw += bf2f(vv.w);
    }
    vred[jq][c4 * 4 + 0] = ax; vred[jq][c4 * 4 + 1] = ay;
    vred[jq][c4 * 4 + 2] = az; vred[jq][c4 * 4 + 3] = aw;
    __syncthreads();
    if (jq == 0) {
#pragma unroll
        for (int c = 0; c < 4; ++c) {
            int o = c4 * 4 + c;
            vsum[b * 256 + o] = vred[0][o] + vred[1][o] + vred[2][o] + vred[3][o];
        }
    }
}

// ============ slots LN -> sln bf16, slots -> hp bf16, zero sums ============
__global__ __launch_bounds__(256) void k_slots_ln(const float* __restrict__ sp,
                                                  const float* __restrict__ lg,
                                                  const float* __restrict__ lb,
                                                  u16* __restrict__ sln, u16* __restrict__ hpb,
                                                  float* __restrict__ sums) {
    int t = threadIdx.x, w = t >> 6, lane = t & 63;
    if (blockIdx.x < 8) sums[blockIdx.x * 256 + t] = 0.f;
    int r = blockIdx.x * 4 + w;
    float4 v = *(const float4*)(sp + (size_t)r * 256 + lane * 4);
    float s1 = v.x + v.y + v.z + v.w;
    float s2 = v.x * v.x + v.y * v.y + v.z * v.z + v.w * v.w;
#pragma unroll
    for (int off = 32; off >= 1; off >>= 1) {
        s1 += __shfl_xor(s1, off);
        s2 += __shfl_xor(s2, off);
    }
    float m = s1 * (1.f / 256.f);
    float rs = rsqrtf(s2 * (1.f / 256.f) - m * m + 1e-5f);
    float4 g = *(const float4*)(lg + lane * 4);
    float4 b = *(const float4*)(lb + lane * 4);
    ushort4 o, hp;
    o.x = f2bf((v.x - m) * rs * g.x + b.x); o.y = f2bf((v.y - m) * rs * g.y + b.y);
    o.z = f2bf((v.z - m) * rs * g.z + b.z); o.w = f2bf((v.w - m) * rs * g.w + b.w);
    hp.x = f2bf(v.x); hp.y = f2bf(v.y); hp.z = f2bf(v.z); hp.w = f2bf(v.w);
    *(ushort4*)(sln + (size_t)r * 256 + lane * 4) = o;
    *(ushort4*)(hpb + (size_t)r * 256 + lane * 4) = hp;
}

// ============ dots (MFMA) + joint softmax + updates partial (MFMA) ============
// grid (64 jb, 32 b); wave = head h; 64 j per block.
__global__ __launch_bounds__(256) void k_dots(const u16* __restrict__ qb,
                                              const u16* __restrict__ kb,
                                              const u16* __restrict__ vb,
                                              float* __restrict__ part,
                                              float* __restrict__ sums,
                                              float* __restrict__ out_attn, int last) {
    __shared__ float dots_s[64 * 65];
    __shared__ float attn_s[64 * 65];
    __shared__ float aout_s[64 * 16];
    int t = threadIdx.x, w = t >> 6, lane = t & 63;
    int b = blockIdx.y, jb = blockIdx.x, j0 = jb * 64;
    int h = w, i15 = lane & 15, qq = lane >> 4;

    short8 afq[2];
#pragma unroll
    for (int kf = 0; kf < 2; ++kf)
        afq[kf] = *(const short8*)(qb + (size_t)(b * 16 + i15) * 256 + h * 64 + kf * 32 + qq * 8);
#pragma unroll
    for (int jt = 0; jt < 4; ++jt) {
        floatx4 acc = (floatx4)(0.f);
#pragma unroll
        for (int kf = 0; kf < 2; ++kf) {
            short8 bf = *(const short8*)(kb + ((size_t)b * 4096 + j0 + jt * 16 + i15) * 256 + h * 64 + kf * 32 + qq * 8);
            acc = __builtin_amdgcn_mfma_f32_16x16x32_bf16(afq[kf], bf, acc, 0, 0, 0);
        }
#pragma unroll
        for (int r = 0; r < 4; ++r)
            dots_s[(jt * 16 + i15) * 65 + h * 16 + qq * 4 + r] = acc[r];
    }
    __syncthreads();
    float ssum = 0.f;
#pragma unroll
    for (int jj = 0; jj < 16; ++jj) {
        int jl = w * 16 + jj;
        float d = dots_s[jl * 65 + lane];
        float mx = d;
#pragma unroll
        for (int off = 32; off >= 1; off >>= 1) mx = fmaxf(mx, __shfl_xor(mx, off));
        float e = __expf(d - mx);
        float sm = e;
#pragma unroll
        for (int off = 32; off >= 1; off >>= 1) sm += __shfl_xor(sm, off);
        float a = e / sm;
        attn_s[jl * 65 + lane] = a;
        ssum += a;
        if (last) {
            float am = a + __shfl_xor(a, 16);
            am += __shfl_xor(am, 32);
            if (lane < 16) aout_s[jl * 16 + lane] = am * 0.25f;
        }
    }
    atomicAdd(&sums[b * 64 + lane], ssum);
    __syncthreads();
    short8 afa[2];
#pragma unroll
    for (int kf = 0; kf < 2; ++kf) {
        union { short8 s; u16 e[8]; } u;
#pragma unroll
        for (int jj = 0; jj < 8; ++jj)
            u.e[jj] = f2bf(attn_s[(kf * 32 + qq * 8 + jj) * 65 + h * 16 + i15]);
        afa[kf] = u.s;
    }
#pragma unroll
    for (int nt = 0; nt < 4; ++nt) {
        floatx4 acc = (floatx4)(0.f);
#pragma unroll
        for (int kf = 0; kf < 2; ++kf) {
            union { short8 s; u16 e[8]; } u;
#pragma unroll
            for (int jj = 0; jj < 8; ++jj)
                u.e[jj] = vb[((size_t)b * 4096 + j0 + kf * 32 + qq * 8 + jj) * 256 + h * 64 + nt * 16 + i15];
            acc = __builtin_amdgcn_mfma_f32_16x16x32_bf16(afa[kf], u.s, acc, 0, 0, 0);
        }
#pragma unroll
        for (int r = 0; r < 4; ++r)
            part[((size_t)b * 64 + jb) * 4096 + h * 1024 + (qq * 4 + r) * 64 + nt * 16 + i15] = acc[r];
    }
    if (last) {
        __syncthreads();
        int i = t >> 4, jq4 = (t & 15) * 4;
        float4 v;
        v.x = aout_s[(jq4 + 0) * 16 + i];
        v.y = aout_s[(jq4 + 1) * 16 + i];
        v.z = aout_s[(jq4 + 2) * 16 + i];
        v.w = aout_s[(jq4 + 3) * 16 + i];
        *(float4*)(out_attn + ((size_t)b * 16 + i) * 4096 + j0 + jq4) = v;
    }
}

// ============ reduce partials -> u bf16 (eps-normalized updates) ============
__global__ __launch_bounds__(256) void k_ured(const float* __restrict__ part,
                                              const float* __restrict__ sums,
                                              const float* __restrict__ vsum,
                                              u16* __restrict__ ub) {
    int b = blockIdx.x, t = threadIdx.x;
    float acc[4][4];
#pragma unroll
    for (int g = 0; g < 4; ++g)
#pragma unroll
        for (int c = 0; c < 4; ++c) acc[g][c] = 0.f;
    const float* pb = part + (size_t)b * 64 * 4096;
    for (int jb = 0; jb < 64; ++jb) {
#pragma unroll
        for (int g = 0; g < 4; ++g) {
            float4 p = *(const float4*)(pb + (size_t)jb * 4096 + g * 1024 + t * 4);
            acc[g][0] += p.x; acc[g][1] += p.y; acc[g][2] += p.z; acc[g][3] += p.w;
        }
    }
    int i = t >> 4, dq = t & 15;
#pragma unroll
    for (int g = 0; g < 4; ++g) {
        float rinv = 1.f / (sums[b * 64 + g * 16 + i] + 4096.f * EPS_ATTN);
        float4 vs = *(const float4*)(vsum + b * 256 + g * 64 + dq * 4);
        ushort4 o;
        o.x = f2bf((acc[g][0] + EPS_ATTN * vs.x) * rinv);
        o.y = f2bf((acc[g][1] + EPS_ATTN * vs.y) * rinv);
        o.z = f2bf((acc[g][2] + EPS_ATTN * vs.z) * rinv);
        o.w = f2bf((acc[g][3] + EPS_ATTN * vs.w) * rinv);
        *(ushort4*)(ub + ((size_t)b * 16 + i) * 256 + g * 64 + dq * 4) = o;
    }
}

// ============ gate combine + hn + LN -> hln bf16 ============
__global__ __launch_bounds__(256) void k_gates(const float* __restrict__ gi,
                                               const float* __restrict__ gh,
                                               const float* __restrict__ sp,
                                               const float* __restrict__ bih,
                                               const float* __restrict__ bhh,
                                               const float* __restrict__ ffg,
                                               const float* __restrict__ ffb,
                                               float* __restrict__ hn_ws,
                                               u16* __restrict__ hln) {
    int t = threadIdx.x, w = t >> 6, lane = t & 63;
    int r = blockIdx.x * 4 + w;
    const float4* gi4 = (const float4*)(gi + (size_t)r * 768);
    const float4* gh4 = (const float4*)(gh + (size_t)r * 768);
    const float4* bi4 = (const float4*)bih;
    const float4* bh4 = (const float4*)bhh;
    float4 gir = gi4[lane], giz = gi4[64 + lane], gin = gi4[128 + lane];
    float4 ghr = gh4[lane], ghz = gh4[64 + lane], ghn = gh4[128 + lane];
    float4 bir = bi4[lane], biz = bi4[64 + lane], bin = bi4[128 + lane];
    float4 bhr = bh4[lane], bhz = bh4[64 + lane], bhn = bh4[128 + lane];
    float4 hp = *(const float4*)(sp + (size_t)r * 256 + lane * 4);
    float4 hn;
    {
        float rg, zg, ng;
        rg = sigm(gir.x + bir.x + ghr.x + bhr.x); zg = sigm(giz.x + biz.x + ghz.x + bhz.x);
        ng = tanhf(gin.x + bin.x + rg * (ghn.x + bhn.x)); hn.x = (1.f - zg) * ng + zg * hp.x;
        rg = sigm(gir.y + bir.y + ghr.y + bhr.y); zg = sigm(giz.y + biz.y + ghz.y + bhz.y);
        ng = tanhf(gin.y + bin.y + rg * (ghn.y + bhn.y)); hn.y = (1.f - zg) * ng + zg * hp.y;
        rg = sigm(gir.z + bir.z + ghr.z + bhr.z); zg = sigm(giz.z + biz.z + ghz.z + bhz.z);
        ng = tanhf(gin.z + bin.z + rg * (ghn.z + bhn.z)); hn.z = (1.f - zg) * ng + zg * hp.z;
        rg = sigm(gir.w + bir.w + ghr.w + bhr.w); zg = sigm(giz.w + biz.w + ghz.w + bhz.w);
        ng = tanhf(gin.w + bin.w + rg * (ghn.w + bhn.w)); hn.w = (1.f - zg) * ng + zg * hp.w;
    }
    *(float4*)(hn_ws + (size_t)r * 256 + lane * 4) = hn;
    float s1 = hn.x + hn.y + hn.z + hn.w;
    float s2 = hn.x * hn.x + hn.y * hn.y + hn.z * hn.z + hn.w * hn.w;
#pragma unroll
    for (int off = 32; off >= 1; off >>= 1) {
        s1 += __shfl_xor(s1, off);
        s2 += __shfl_xor(s2, off);
    }
    float m = s1 * (1.f / 256.f);
    float rs = rsqrtf(s2 * (1.f / 256.f) - m * m + 1e-5f);
    float4 g = *(const float4*)(ffg + lane * 4);
    float4 b = *(const float4*)(ffb + lane * 4);
    ushort4 o;
    o.x = f2bf((hn.x - m) * rs * g.x + b.x); o.y = f2bf((hn.y - m) * rs * g.y + b.y);
    o.z = f2bf((hn.z - m) * rs * g.z + b.z); o.w = f2bf((hn.w - m) * rs * g.w + b.w);
    *(ushort4*)(hln + (size_t)r * 256 + lane * 4) = o;
}

extern "C" void kernel_launch(void* const* d_in, const int* in_sizes, int n_in,
                              void* d_out, int out_size, void* d_ws, size_t ws_size,
                              hipStream_t stream) {
    const float* inputs   = (const float*)d_in[0];
    const float* cond     = (const float*)d_in[1];
    const float* to_q_w   = (const float*)d_in[2];
    const float* to_k_w   = (const float*)d_in[3];
    const float* to_v_w   = (const float*)d_in[4];
    const float* gru_w_ih = (const float*)d_in[5];
    const float* gru_w_hh = (const float*)d_in[6];
    const float* gru_b_ih = (const float*)d_in[7];
    const float* gru_b_hh = (const float*)d_in[8];
    const float* ln_in_g  = (const float*)d_in[9];
    const float* ln_in_b  = (const float*)d_in[10];
    const float* ln_sl_g  = (const float*)d_in[11];
    const float* ln_sl_b  = (const float*)d_in[12];
    const float* ff_ln_g  = (const float*)d_in[13];
    const float* ff_ln_b  = (const float*)d_in[14];
    const float* ff_w1    = (const float*)d_in[15];
    const float* ff_b1    = (const float*)d_in[16];
    const float* ff_w2    = (const float*)d_in[17];
    const float* ff_b2    = (const float*)d_in[18];

    float* out_slots = (float*)d_out;
    float* out_attn  = (float*)d_out + 131072;

    // ---- workspace carve (bytes) ----
    char* p = (char*)d_ws;
    u16* kbuf = (u16*)p;                 p += (size_t)M_TOKENS * 256 * 2;   // 67.1 MB
    u16* vbuf = (u16*)p;                 p += (size_t)M_TOKENS * 256 * 2;   // 67.1 MB
    char* region = p;                    p += (size_t)MCHUNK * FEAT * 2;    // 50.3 MB (aliased)
    u16*   xln_c = (u16*)region;                       // kv phase
    float* part  = (float*)region;                     // iter: 32*64*4096 f = 33.5 MB
    float* gi    = (float*)(region + 33554432);        // 1.5 MB
    float* gh    = (float*)(region + 33554432 + 1572864);
    u16* wall = (u16*)p;                 p += (size_t)W_TOTAL * 2;
    u16* qbuf = (u16*)p;                 p += 131072 * 2;
    u16* sln  = (u16*)p;                 p += 131072 * 2;
    u16* hpb  = (u16*)p;                 p += 131072 * 2;
    u16* ub   = (u16*)p;                 p += 131072 * 2;
    u16* hln  = (u16*)p;                 p += 131072 * 2;
    u16* g1   = (u16*)p;                 p += (size_t)512 * 1024 * 2;
    float* slots_ws = (float*)p;         p += 131072 * 4;
    float* hn_ws    = (float*)p;         p += 131072 * 4;
    float* sums     = (float*)p;         p += 2048 * 4;
    float* vsum     = (float*)p;         p += 8192 * 4;

    k_wcvt<<<(W_TOTAL / 4 + 255) / 256, 256, 0, stream>>>(
        to_k_w, to_v_w, to_q_w, gru_w_ih, gru_w_hh, ff_w1, ff_w2, wall);

    for (int c = 0; c < 4; ++c) {
        k_ln_bf16<<<MCHUNK / 4, 256, 0, stream>>>(
            inputs + (size_t)c * MCHUNK * FEAT, ln_in_g, ln_in_b, xln_c);
        gemm_bt<768, 0><<<dim3(4, MCHUNK / 128, 1), 256, 0, stream>>>(
            xln_c, nullptr, wall + OFF_WKV, nullptr,
            kbuf + (size_t)c * MCHUNK * 256, vbuf + (size_t)c * MCHUNK * 256,
            nullptr, nullptr, nullptr, 256);
    }
    k_vsum<<<32, 256, 0, stream>>>(vbuf, vsum);

    for (int it = 0; it < 3; ++it) {
        const float* sp = (it == 0) ? cond : slots_ws;
        int last = (it == 2) ? 1 : 0;
        k_slots_ln<<<128, 256, 0, stream>>>(sp, ln_sl_g, ln_sl_b, sln, hpb, sums);
        gemm_bt<256, 1><<<dim3(2, 4, 1), 256, 0, stream>>>(
            sln, nullptr, wall + OFF_WQ, nullptr, qbuf, nullptr, nullptr, nullptr, nullptr, 256);
        k_dots<<<dim3(64, 32), 256, 0, stream>>>(qbuf, kbuf, vbuf, part, sums, out_attn, last);
        k_ured<<<32, 256, 0, stream>>>(part, sums, vsum, ub);
        gemm_bt<256, 2><<<dim3(6, 4, 2), 256, 0, stream>>>(
            ub, hpb, wall + OFF_WIH, wall + OFF_WHH, gi, gh, nullptr, nullptr, nullptr, 768);
        k_gates<<<128, 256, 0, stream>>>(gi, gh, sp, gru_b_ih, gru_b_hh,
                                         ff_ln_g, ff_ln_b, hn_ws, hln);
        gemm_bt<256, 3><<<dim3(8, 4, 1), 256, 0, stream>>>(
            hln, nullptr, wall + OFF_W1, nullptr, g1, nullptr, ff_b1, nullptr, nullptr, 1024);
        gemm_bt<1024, 4><<<dim3(2, 4, 1), 256, 0, stream>>>(
            g1, nullptr, wall + OFF_W2, nullptr, slots_ws, nullptr, ff_b2, hn_ws,
            last ? out_slots : slots_ws, 256);
    }
}

// Round 3
// 1123.739 us; speedup vs baseline: 1.9166x; 1.3853x over previous
//
#include <hip/hip_runtime.h>

#define B_SZ 32
#define N_TOK 4096
#define FEAT 768
#define DIM 256
#define NSLOT 16
#define NH 4
#define DH 64
#define M_TOKENS 131072
#define SCALE 0.125f
#define EPS_ATTN 1e-8f
#define MCHUNK 32768      // kv gemm M-chunk (4 chunks)

typedef unsigned short u16;
typedef __attribute__((ext_vector_type(8))) short short8;
typedef __attribute__((ext_vector_type(4))) float floatx4;

__device__ __forceinline__ u16 f2bf(float f) {
    unsigned int u = __float_as_uint(f);
    u += 0x7FFFu + ((u >> 16) & 1u);
    return (u16)(u >> 16);
}
__device__ __forceinline__ float bf2f(u16 u) {
    return __uint_as_float(((unsigned int)u) << 16);
}
__device__ __forceinline__ void gl_lds16(const void* g, void* l) {
    __builtin_amdgcn_global_load_lds((const __attribute__((address_space(1))) void*)g,
                                     (__attribute__((address_space(3))) void*)l, 16, 0, 0);
}
__device__ __forceinline__ float sigm(float x) { return 1.f / (1.f + expf(-x)); }

// ============ generic bf16 MFMA GEMM: C[M,N] = A[M,K] @ B[N,K]^T ============
template<int TK, int EPI>
__global__ __launch_bounds__(256) void gemm_bt(
    const u16* __restrict__ A0, const u16* __restrict__ A1,
    const u16* __restrict__ B0, const u16* __restrict__ B1,
    void* __restrict__ C0, void* __restrict__ C1,
    const float* __restrict__ bias, const float* __restrict__ res,
    float* __restrict__ out2, int ldc) {
    __shared__ u16 As[128 * 32];
    __shared__ u16 Bs[128 * 32];
    int t = threadIdx.x, w = t >> 6, lane = t & 63;
    int n0 = blockIdx.x * 128;
    size_t m0 = (size_t)blockIdx.y * 128;
    const u16* A = (blockIdx.z && A1) ? A1 : A0;
    const u16* B = (blockIdx.z && B1) ? B1 : B0;

    floatx4 acc[2][8];
#pragma unroll
    for (int mt = 0; mt < 2; ++mt)
#pragma unroll
        for (int nt = 0; nt < 8; ++nt) acc[mt][nt] = (floatx4)(0.f);

    int srow = (lane >> 2), seg = lane & 3;
    for (int k0 = 0; k0 < TK; k0 += 32) {
#pragma unroll
        for (int c = 0; c < 2; ++c) {
            int row = w * 32 + c * 16 + srow;
            gl_lds16(A + (m0 + row) * TK + k0 + seg * 8, &As[(w * 32 + c * 16) * 32]);
            gl_lds16(B + (size_t)(n0 + row) * TK + k0 + seg * 8, &Bs[(w * 32 + c * 16) * 32]);
        }
        __syncthreads();
        short8 af[2];
#pragma unroll
        for (int mt = 0; mt < 2; ++mt)
            af[mt] = *(const short8*)&As[(w * 32 + mt * 16 + (lane & 15)) * 32 + (lane >> 4) * 8];
        short8 bfr[8];
#pragma unroll
        for (int nt = 0; nt < 8; ++nt)
            bfr[nt] = *(const short8*)&Bs[(nt * 16 + (lane & 15)) * 32 + (lane >> 4) * 8];
#pragma unroll
        for (int mt = 0; mt < 2; ++mt)
#pragma unroll
            for (int nt = 0; nt < 8; ++nt)
                acc[mt][nt] = __builtin_amdgcn_mfma_f32_16x16x32_bf16(af[mt], bfr[nt], acc[mt][nt], 0, 0, 0);
        __syncthreads();
    }
#pragma unroll
    for (int mt = 0; mt < 2; ++mt)
#pragma unroll
        for (int nt = 0; nt < 8; ++nt)
#pragma unroll
            for (int rr = 0; rr < 4; ++rr) {
                size_t row = m0 + w * 32 + mt * 16 + (lane >> 4) * 4 + rr;
                int col = n0 + nt * 16 + (lane & 15);
                float v = acc[mt][nt][rr];
                if (EPI == 0) {
                    if (col < 256) ((u16*)C0)[row * 256 + col] = f2bf(v);
                    else           ((u16*)C1)[row * 256 + col - 256] = f2bf(v);
                } else if (EPI == 1) {
                    ((u16*)C0)[row * (size_t)ldc + col] = f2bf(v);
                } else if (EPI == 2) {
                    float* Cf = (float*)(blockIdx.z ? C1 : C0);
                    Cf[row * (size_t)ldc + col] = v;
                } else if (EPI == 3) {
                    float a = v + bias[col];
                    float g = 0.5f * a * (1.f + erff(a * 0.70710678118654752f));
                    ((u16*)C0)[row * (size_t)ldc + col] = f2bf(g);
                } else if (EPI == 4) {
                    float a = v + bias[col] + res[row * 256 + col];
                    ((float*)C0)[row * 256 + col] = a;
                    out2[row * 256 + col] = a;
                }
            }
}

// ============ LN(inputs) -> bf16, one wave per row ============
__global__ __launch_bounds__(256) void k_ln_bf16(const float* __restrict__ x,
                                                 const float* __restrict__ lg,
                                                 const float* __restrict__ lb,
                                                 u16* __restrict__ xln) {
    int w = threadIdx.x >> 6, lane = threadIdx.x & 63;
    size_t row = (size_t)blockIdx.x * 4 + w;
    const float4* x4 = (const float4*)(x + row * FEAT);
    float4 a[3];
    float s = 0.f, sq = 0.f;
#pragma unroll
    for (int p = 0; p < 3; ++p) {
        a[p] = x4[p * 64 + lane];
        s += a[p].x + a[p].y + a[p].z + a[p].w;
        sq += a[p].x * a[p].x + a[p].y * a[p].y + a[p].z * a[p].z + a[p].w * a[p].w;
    }
#pragma unroll
    for (int off = 32; off >= 1; off >>= 1) {
        s += __shfl_xor(s, off);
        sq += __shfl_xor(sq, off);
    }
    float m = s * (1.f / 768.f);
    float rs = rsqrtf(sq * (1.f / 768.f) - m * m + 1e-5f);
#pragma unroll
    for (int p = 0; p < 3; ++p) {
        float4 g = *(const float4*)(lg + (p * 64 + lane) * 4);
        float4 b = *(const float4*)(lb + (p * 64 + lane) * 4);
        ushort4 o;
        o.x = f2bf((a[p].x - m) * rs * g.x + b.x);
        o.y = f2bf((a[p].y - m) * rs * g.y + b.y);
        o.z = f2bf((a[p].z - m) * rs * g.z + b.z);
        o.w = f2bf((a[p].w - m) * rs * g.w + b.w);
        *(ushort4*)(xln + row * FEAT + (p * 64 + lane) * 4) = o;
    }
}

// ============ weight convert -> bf16 ============
#define OFF_WKV 0
#define OFF_WQ  393216
#define OFF_WIH 458752
#define OFF_WHH 655360
#define OFF_W1  851968
#define OFF_W2  1114112
#define W_TOTAL 1376256
__global__ __launch_bounds__(256) void k_wcvt(
    const float* __restrict__ wk, const float* __restrict__ wv,
    const float* __restrict__ wq, const float* __restrict__ wih,
    const float* __restrict__ whh, const float* __restrict__ w1,
    const float* __restrict__ w2, u16* __restrict__ wall) {
    int base = (blockIdx.x * 256 + threadIdx.x) * 4;
    if (base >= W_TOTAL) return;
#pragma unroll
    for (int q = 0; q < 4; ++q) {
        int id = base + q;
        float v;
        if (id < OFF_WQ) {
            int r = id / 768, c = id - r * 768;
            v = (r < 256) ? wk[r * 768 + c] : wv[(r - 256) * 768 + c];
        } else if (id < OFF_WIH) v = wq[id - OFF_WQ] * SCALE;
        else if (id < OFF_W1)    v = (id < OFF_WHH) ? wih[id - OFF_WIH] : whh[id - OFF_WHH];
        else if (id < OFF_W2)    v = w1[id - OFF_W1];
        else                     v = w2[id - OFF_W2];
        wall[id] = f2bf(v);
    }
}

// ============ transpose v[b][j][c] -> vT[b][c][j]  (64j x 256c tiles) ============
__global__ __launch_bounds__(256) void k_vt(const u16* __restrict__ vb,
                                            u16* __restrict__ vt) {
    __shared__ u16 lds[256 * 66];
    int t = threadIdx.x;
    int b = blockIdx.y, j0 = blockIdx.x * 64;
#pragma unroll
    for (int it = 0; it < 16; ++it) {
        int flat = it * 256 + t;
        int j = flat >> 6, c4 = flat & 63;
        ushort4 vv = *(const ushort4*)(vb + ((size_t)b * 4096 + j0 + j) * 256 + c4 * 4);
        lds[(c4 * 4 + 0) * 66 + j] = vv.x;
        lds[(c4 * 4 + 1) * 66 + j] = vv.y;
        lds[(c4 * 4 + 2) * 66 + j] = vv.z;
        lds[(c4 * 4 + 3) * 66 + j] = vv.w;
    }
    __syncthreads();
#pragma unroll
    for (int it = 0; it < 8; ++it) {
        int flat = it * 256 + t;
        int d = flat >> 3, jseg = flat & 7;
        const unsigned int* s32 = (const unsigned int*)(lds + d * 66 + jseg * 8);
        uint4 o;
        o.x = s32[0]; o.y = s32[1]; o.z = s32[2]; o.w = s32[3];
        *(uint4*)(vt + ((size_t)b * 256 + d) * 4096 + j0 + jseg * 8) = o;
    }
}

// ============ vsum[b*256+c] = sum_j vT row (one wave per row) ============
__global__ __launch_bounds__(256) void k_vsum(const u16* __restrict__ vt,
                                              float* __restrict__ vsum) {
    int w = threadIdx.x >> 6, lane = threadIdx.x & 63;
    int r = blockIdx.x * 4 + w;
    const short8* row = (const short8*)(vt + (size_t)r * 4096);
    float s = 0.f;
#pragma unroll
    for (int it = 0; it < 8; ++it) {
        union { short8 v; u16 e[8]; } u;
        u.v = row[it * 64 + lane];
#pragma unroll
        for (int q = 0; q < 8; ++q) s += bf2f(u.e[q]);
    }
#pragma unroll
    for (int off = 32; off >= 1; off >>= 1) s += __shfl_xor(s, off);
    if (lane == 0) vsum[r] = s;
}

// ============ slots LN -> sln bf16, slots -> hp bf16, zero sums ============
__global__ __launch_bounds__(256) void k_slots_ln(const float* __restrict__ sp,
                                                  const float* __restrict__ lg,
                                                  const float* __restrict__ lb,
                                                  u16* __restrict__ sln, u16* __restrict__ hpb,
                                                  float* __restrict__ sums) {
    int t = threadIdx.x, w = t >> 6, lane = t & 63;
    if (blockIdx.x < 8) sums[blockIdx.x * 256 + t] = 0.f;
    int r = blockIdx.x * 4 + w;
    float4 v = *(const float4*)(sp + (size_t)r * 256 + lane * 4);
    float s1 = v.x + v.y + v.z + v.w;
    float s2 = v.x * v.x + v.y * v.y + v.z * v.z + v.w * v.w;
#pragma unroll
    for (int off = 32; off >= 1; off >>= 1) {
        s1 += __shfl_xor(s1, off);
        s2 += __shfl_xor(s2, off);
    }
    float m = s1 * (1.f / 256.f);
    float rs = rsqrtf(s2 * (1.f / 256.f) - m * m + 1e-5f);
    float4 g = *(const float4*)(lg + lane * 4);
    float4 b = *(const float4*)(lb + lane * 4);
    ushort4 o, hp;
    o.x = f2bf((v.x - m) * rs * g.x + b.x); o.y = f2bf((v.y - m) * rs * g.y + b.y);
    o.z = f2bf((v.z - m) * rs * g.z + b.z); o.w = f2bf((v.w - m) * rs * g.w + b.w);
    hp.x = f2bf(v.x); hp.y = f2bf(v.y); hp.z = f2bf(v.z); hp.w = f2bf(v.w);
    *(ushort4*)(sln + (size_t)r * 256 + lane * 4) = o;
    *(ushort4*)(hpb + (size_t)r * 256 + lane * 4) = hp;
}

// ============ dots (MFMA) + joint softmax + updates partial (MFMA, vT) ============
__global__ __launch_bounds__(256) void k_dots(const u16* __restrict__ qb,
                                              const u16* __restrict__ kb,
                                              const u16* __restrict__ vt,
                                              float* __restrict__ part,
                                              float* __restrict__ sums,
                                              float* __restrict__ out_attn, int last) {
    __shared__ float dots_s[64 * 65];
    __shared__ float attn_s[64 * 65];
    __shared__ float aout_s[64 * 16];
    int t = threadIdx.x, w = t >> 6, lane = t & 63;
    int b = blockIdx.y, jb = blockIdx.x, j0 = jb * 64;
    int h = w, i15 = lane & 15, qq = lane >> 4;

    short8 afq[2];
#pragma unroll
    for (int kf = 0; kf < 2; ++kf)
        afq[kf] = *(const short8*)(qb + (size_t)(b * 16 + i15) * 256 + h * 64 + kf * 32 + qq * 8);
#pragma unroll
    for (int jt = 0; jt < 4; ++jt) {
        floatx4 acc = (floatx4)(0.f);
#pragma unroll
        for (int kf = 0; kf < 2; ++kf) {
            short8 bf = *(const short8*)(kb + ((size_t)b * 4096 + j0 + jt * 16 + i15) * 256 + h * 64 + kf * 32 + qq * 8);
            acc = __builtin_amdgcn_mfma_f32_16x16x32_bf16(afq[kf], bf, acc, 0, 0, 0);
        }
#pragma unroll
        for (int r = 0; r < 4; ++r)
            dots_s[(jt * 16 + i15) * 65 + h * 16 + qq * 4 + r] = acc[r];
    }
    __syncthreads();
    float ssum = 0.f;
#pragma unroll
    for (int jj = 0; jj < 16; ++jj) {
        int jl = w * 16 + jj;
        float d = dots_s[jl * 65 + lane];
        float mx = d;
#pragma unroll
        for (int off = 32; off >= 1; off >>= 1) mx = fmaxf(mx, __shfl_xor(mx, off));
        float e = __expf(d - mx);
        float sm = e;
#pragma unroll
        for (int off = 32; off >= 1; off >>= 1) sm += __shfl_xor(sm, off);
        float a = e / sm;
        attn_s[jl * 65 + lane] = a;
        ssum += a;
        if (last) {
            float am = a + __shfl_xor(a, 16);
            am += __shfl_xor(am, 32);
            if (lane < 16) aout_s[jl * 16 + lane] = am * 0.25f;
        }
    }
    atomicAdd(&sums[b * 64 + lane], ssum);
    __syncthreads();
    short8 afa[2];
#pragma unroll
    for (int kf = 0; kf < 2; ++kf) {
        union { short8 s; u16 e[8]; } u;
#pragma unroll
        for (int jj = 0; jj < 8; ++jj)
            u.e[jj] = f2bf(attn_s[(kf * 32 + qq * 8 + jj) * 65 + h * 16 + i15]);
        afa[kf] = u.s;
    }
#pragma unroll
    for (int nt = 0; nt < 4; ++nt) {
        floatx4 acc = (floatx4)(0.f);
#pragma unroll
        for (int kf = 0; kf < 2; ++kf) {
            short8 bf = *(const short8*)(vt + ((size_t)b * 256 + h * 64 + nt * 16 + i15) * 4096 + j0 + kf * 32 + qq * 8);
            acc = __builtin_amdgcn_mfma_f32_16x16x32_bf16(afa[kf], bf, acc, 0, 0, 0);
        }
#pragma unroll
        for (int r = 0; r < 4; ++r)
            part[((size_t)b * 64 + jb) * 4096 + h * 1024 + (qq * 4 + r) * 64 + nt * 16 + i15] = acc[r];
    }
    if (last) {
        __syncthreads();
        int i = t >> 4, jq4 = (t & 15) * 4;
        float4 v;
        v.x = aout_s[(jq4 + 0) * 16 + i];
        v.y = aout_s[(jq4 + 1) * 16 + i];
        v.z = aout_s[(jq4 + 2) * 16 + i];
        v.w = aout_s[(jq4 + 3) * 16 + i];
        *(float4*)(out_attn + ((size_t)b * 16 + i) * 4096 + j0 + jq4) = v;
    }
}

// ============ reduce partials -> u bf16 (parallel, 512 blocks) ============
__global__ __launch_bounds__(256) void k_ured(const float* __restrict__ part,
                                              const float* __restrict__ sums,
                                              const float* __restrict__ vsum,
                                              u16* __restrict__ ub) {
    int r = blockIdx.x, t = threadIdx.x;
    int b = r >> 4;
    int c = (r & 15) * 256 + t;
    const float* pb = part + (size_t)b * 64 * 4096 + c;
    float acc = 0.f;
#pragma unroll 16
    for (int jb = 0; jb < 64; ++jb) acc += pb[(size_t)jb * 4096];
    int h = c >> 10, i = (c >> 6) & 15, d = c & 63;
    float rinv = 1.f / (sums[b * 64 + h * 16 + i] + 4096.f * EPS_ATTN);
    float vs = vsum[b * 256 + h * 64 + d];
    ub[((size_t)b * 16 + i) * 256 + h * 64 + d] = f2bf((acc + EPS_ATTN * vs) * rinv);
}

// ============ gate combine + hn + LN -> hln bf16 ============
__global__ __launch_bounds__(256) void k_gates(const float* __restrict__ gi,
                                               const float* __restrict__ gh,
                                               const float* __restrict__ sp,
                                               const float* __restrict__ bih,
                                               const float* __restrict__ bhh,
                                               const float* __restrict__ ffg,
                                               const float* __restrict__ ffb,
                                               float* __restrict__ hn_ws,
                                               u16* __restrict__ hln) {
    int t = threadIdx.x, w = t >> 6, lane = t & 63;
    int r = blockIdx.x * 4 + w;
    const float4* gi4 = (const float4*)(gi + (size_t)r * 768);
    const float4* gh4 = (const float4*)(gh + (size_t)r * 768);
    const float4* bi4 = (const float4*)bih;
    const float4* bh4 = (const float4*)bhh;
    float4 gir = gi4[lane], giz = gi4[64 + lane], gin = gi4[128 + lane];
    float4 ghr = gh4[lane], ghz = gh4[64 + lane], ghn = gh4[128 + lane];
    float4 bir = bi4[lane], biz = bi4[64 + lane], bin = bi4[128 + lane];
    float4 bhr = bh4[lane], bhz = bh4[64 + lane], bhn = bh4[128 + lane];
    float4 hp = *(const float4*)(sp + (size_t)r * 256 + lane * 4);
    float4 hn;
    {
        float rg, zg, ng;
        rg = sigm(gir.x + bir.x + ghr.x + bhr.x); zg = sigm(giz.x + biz.x + ghz.x + bhz.x);
        ng = tanhf(gin.x + bin.x + rg * (ghn.x + bhn.x)); hn.x = (1.f - zg) * ng + zg * hp.x;
        rg = sigm(gir.y + bir.y + ghr.y + bhr.y); zg = sigm(giz.y + biz.y + ghz.y + bhz.y);
        ng = tanhf(gin.y + bin.y + rg * (ghn.y + bhn.y)); hn.y = (1.f - zg) * ng + zg * hp.y;
        rg = sigm(gir.z + bir.z + ghr.z + bhr.z); zg = sigm(giz.z + biz.z + ghz.z + bhz.z);
        ng = tanhf(gin.z + bin.z + rg * (ghn.z + bhn.z)); hn.z = (1.f - zg) * ng + zg * hp.z;
        rg = sigm(gir.w + bir.w + ghr.w + bhr.w); zg = sigm(giz.w + biz.w + ghz.w + bhz.w);
        ng = tanhf(gin.w + bin.w + rg * (ghn.w + bhn.w)); hn.w = (1.f - zg) * ng + zg * hp.w;
    }
    *(float4*)(hn_ws + (size_t)r * 256 + lane * 4) = hn;
    float s1 = hn.x + hn.y + hn.z + hn.w;
    float s2 = hn.x * hn.x + hn.y * hn.y + hn.z * hn.z + hn.w * hn.w;
#pragma unroll
    for (int off = 32; off >= 1; off >>= 1) {
        s1 += __shfl_xor(s1, off);
        s2 += __shfl_xor(s2, off);
    }
    float m = s1 * (1.f / 256.f);
    float rs = rsqrtf(s2 * (1.f / 256.f) - m * m + 1e-5f);
    float4 g = *(const float4*)(ffg + lane * 4);
    float4 b = *(const float4*)(ffb + lane * 4);
    ushort4 o;
    o.x = f2bf((hn.x - m) * rs * g.x + b.x); o.y = f2bf((hn.y - m) * rs * g.y + b.y);
    o.z = f2bf((hn.z - m) * rs * g.z + b.z); o.w = f2bf((hn.w - m) * rs * g.w + b.w);
    *(ushort4*)(hln + (size_t)r * 256 + lane * 4) = o;
}

extern "C" void kernel_launch(void* const* d_in, const int* in_sizes, int n_in,
                              void* d_out, int out_size, void* d_ws, size_t ws_size,
                              hipStream_t stream) {
    const float* inputs   = (const float*)d_in[0];
    const float* cond     = (const float*)d_in[1];
    const float* to_q_w   = (const float*)d_in[2];
    const float* to_k_w   = (const float*)d_in[3];
    const float* to_v_w   = (const float*)d_in[4];
    const float* gru_w_ih = (const float*)d_in[5];
    const float* gru_w_hh = (const float*)d_in[6];
    const float* gru_b_ih = (const float*)d_in[7];
    const float* gru_b_hh = (const float*)d_in[8];
    const float* ln_in_g  = (const float*)d_in[9];
    const float* ln_in_b  = (const float*)d_in[10];
    const float* ln_sl_g  = (const float*)d_in[11];
    const float* ln_sl_b  = (const float*)d_in[12];
    const float* ff_ln_g  = (const float*)d_in[13];
    const float* ff_ln_b  = (const float*)d_in[14];
    const float* ff_w1    = (const float*)d_in[15];
    const float* ff_b1    = (const float*)d_in[16];
    const float* ff_w2    = (const float*)d_in[17];
    const float* ff_b2    = (const float*)d_in[18];

    float* out_slots = (float*)d_out;
    float* out_attn  = (float*)d_out + 131072;

    // ---- workspace carve ----
    char* p = (char*)d_ws;
    u16* kbuf = (u16*)p;                  p += (size_t)M_TOKENS * 256 * 2;  // 67.1 MB
    char* vregion = p;                    p += (size_t)M_TOKENS * 256 * 2;  // 67.1 MB
    u16*   vbuf = (u16*)vregion;                       // kv phase + k_vt only
    float* part = (float*)vregion;                     // iters (33.55 MB), after vT built
    float* gi   = (float*)(vregion + 33554432);        // 1.5 MB
    float* gh   = (float*)(vregion + 35127296);        // 1.5 MB
    char* tregion = p;                    p += (size_t)M_TOKENS * 256 * 2;  // 67.1 MB
    u16* xln_c = (u16*)tregion;                        // kv phase (50.3 MB)
    u16* vT    = (u16*)tregion;                        // after kv phase
    u16* wall = (u16*)p;                  p += (size_t)W_TOTAL * 2;
    u16* qbuf = (u16*)p;                  p += 131072 * 2;
    u16* sln  = (u16*)p;                  p += 131072 * 2;
    u16* hpb  = (u16*)p;                  p += 131072 * 2;
    u16* ub   = (u16*)p;                  p += 131072 * 2;
    u16* hln  = (u16*)p;                  p += 131072 * 2;
    u16* g1   = (u16*)p;                  p += (size_t)512 * 1024 * 2;
    float* slots_ws = (float*)p;          p += 131072 * 4;
    float* hn_ws    = (float*)p;          p += 131072 * 4;
    float* sums     = (float*)p;          p += 2048 * 4;
    float* vsum     = (float*)p;          p += 8192 * 4;

    k_wcvt<<<(W_TOTAL / 4 + 255) / 256, 256, 0, stream>>>(
        to_k_w, to_v_w, to_q_w, gru_w_ih, gru_w_hh, ff_w1, ff_w2, wall);

    for (int c = 0; c < 4; ++c) {
        k_ln_bf16<<<MCHUNK / 4, 256, 0, stream>>>(
            inputs + (size_t)c * MCHUNK * FEAT, ln_in_g, ln_in_b, xln_c);
        gemm_bt<768, 0><<<dim3(4, MCHUNK / 128, 1), 256, 0, stream>>>(
            xln_c, nullptr, wall + OFF_WKV, nullptr,
            kbuf + (size_t)c * MCHUNK * 256, vbuf + (size_t)c * MCHUNK * 256,
            nullptr, nullptr, nullptr, 256);
    }
    k_vt<<<dim3(64, 32), 256, 0, stream>>>(vbuf, vT);   // vbuf dead after this
    k_vsum<<<2048 / 4 * 4 / 4, 256, 0, stream>>>(vT, vsum);  // 2048 rows/4 per block... see grid below

    for (int it = 0; it < 3; ++it) {
        const float* sp = (it == 0) ? cond : slots_ws;
        int last = (it == 2) ? 1 : 0;
        k_slots_ln<<<128, 256, 0, stream>>>(sp, ln_sl_g, ln_sl_b, sln, hpb, sums);
        gemm_bt<256, 1><<<dim3(2, 4, 1), 256, 0, stream>>>(
            sln, nullptr, wall + OFF_WQ, nullptr, qbuf, nullptr, nullptr, nullptr, nullptr, 256);
        k_dots<<<dim3(64, 32), 256, 0, stream>>>(qbuf, kbuf, vT, part, sums, out_attn, last);
        k_ured<<<512, 256, 0, stream>>>(part, sums, vsum, ub);
        gemm_bt<256, 2><<<dim3(6, 4, 2), 256, 0, stream>>>(
            ub, hpb, wall + OFF_WIH, wall + OFF_WHH, gi, gh, nullptr, nullptr, nullptr, 768);
        k_gates<<<128, 256, 0, stream>>>(gi, gh, sp, gru_b_ih, gru_b_hh,
                                         ff_ln_g, ff_ln_b, hn_ws, hln);
        gemm_bt<256, 3><<<dim3(8, 4, 1), 256, 0, stream>>>(
            hln, nullptr, wall + OFF_W1, nullptr, g1, nullptr, ff_b1, nullptr, nullptr, 1024);
        gemm_bt<1024, 4><<<dim3(2, 4, 1), 256, 0, stream>>>(
            g1, nullptr, wall + OFF_W2, nullptr, slots_ws, nullptr, ff_b2, hn_ws,
            last ? out_slots : slots_ws, 256);
    }
}